// Round 1
// baseline (1184.653 us; speedup 1.0000x reference)
//
#include <hip/hip_runtime.h>

#define DEV static __device__ __forceinline__

typedef unsigned short u16;
typedef short bf16x4 __attribute__((ext_vector_type(4)));
typedef short bf16x8 __attribute__((ext_vector_type(8)));
typedef float f32x4 __attribute__((ext_vector_type(4)));

#define B_   2
#define T_   2048
#define D_   2048
#define H_   16
#define KVH_ 4
#define HD_  128

DEV u16 f2bf(float f) {
  union { float f; unsigned u; } v; v.f = f;
  unsigned r = v.u + 0x7fffu + ((v.u >> 16) & 1u);
  return (u16)(r >> 16);
}

DEV float wave_sum(float v) {
#pragma unroll
  for (int o = 1; o < 64; o <<= 1) v += __shfl_xor(v, o);
  return v;
}

#define LOAD_LDS_16B(gptr, lptr)                                                                  \
  __builtin_amdgcn_global_load_lds((const __attribute__((address_space(1))) unsigned int*)(gptr), \
                                   (__attribute__((address_space(3))) unsigned int*)(lptr), 16, 0, 0)

DEV f32x4 mfma32(bf16x8 a, bf16x8 b, f32x4 c) {
  return __builtin_amdgcn_mfma_f32_16x16x32_bf16(a, b, c, 0, 0, 0);
}

#if __has_builtin(__builtin_amdgcn_mfma_f32_16x16x16bf16_1k)
DEV f32x4 mfma16(bf16x4 a, bf16x4 b, f32x4 c) {
  return __builtin_amdgcn_mfma_f32_16x16x16bf16_1k(a, b, c, 0, 0, 0);
}
#elif __has_builtin(__builtin_amdgcn_mfma_f32_16x16x16_bf16_1k)
DEV f32x4 mfma16(bf16x4 a, bf16x4 b, f32x4 c) {
  return __builtin_amdgcn_mfma_f32_16x16x16_bf16_1k(a, b, c, 0, 0, 0);
}
#elif __has_builtin(__builtin_amdgcn_mfma_f32_16x16x16_bf16)
DEV f32x4 mfma16(bf16x4 a, bf16x4 b, f32x4 c) {
  return __builtin_amdgcn_mfma_f32_16x16x16_bf16(a, b, c, 0, 0, 0);
}
#else
DEV f32x4 mfma16(bf16x4 a, bf16x4 b, f32x4 c) {
  asm volatile("v_mfma_f32_16x16x16_bf16 %0, %1, %2, %0\n\ts_nop 7\n\ts_nop 7"
               : "+v"(c) : "v"(a), "v"(b));
  return c;
}
#endif

// ---------------- prep: token-shift mix + bf16 cast ----------------
__global__ __launch_bounds__(256) void prep_x(const float* __restrict__ xq, const float* __restrict__ xk,
                                              const float* __restrict__ xv, const float* __restrict__ mk,
                                              const float* __restrict__ mv, u16* __restrict__ xqb,
                                              u16* __restrict__ xkb, u16* __restrict__ xvb) {
  const int n4 = (B_ * T_ * D_) >> 2;
  for (int i = blockIdx.x * blockDim.x + threadIdx.x; i < n4; i += gridDim.x * blockDim.x) {
    const int idx = i << 2;
    const int d = idx & (D_ - 1);
    const int t = (idx >> 11) & (T_ - 1);
    float4 q = *(const float4*)(xq + idx);
    float4 k = *(const float4*)(xk + idx);
    float4 v = *(const float4*)(xv + idx);
    float4 kp = {0, 0, 0, 0}, vp = {0, 0, 0, 0};
    if (t > 0) {
      kp = *(const float4*)(xk + idx - D_);
      vp = *(const float4*)(xv + idx - D_);
    }
    float4 cmk = *(const float4*)(mk + d);
    float4 cmv = *(const float4*)(mv + d);
    ushort4 qo, ko, vo;
    qo.x = f2bf(q.x); qo.y = f2bf(q.y); qo.z = f2bf(q.z); qo.w = f2bf(q.w);
    ko.x = f2bf(k.x + cmk.x * (kp.x - k.x));
    ko.y = f2bf(k.y + cmk.y * (kp.y - k.y));
    ko.z = f2bf(k.z + cmk.z * (kp.z - k.z));
    ko.w = f2bf(k.w + cmk.w * (kp.w - k.w));
    vo.x = f2bf(v.x + cmv.x * (vp.x - v.x));
    vo.y = f2bf(v.y + cmv.y * (vp.y - v.y));
    vo.z = f2bf(v.z + cmv.z * (vp.z - v.z));
    vo.w = f2bf(v.w + cmv.w * (vp.w - v.w));
    *(ushort4*)(xqb + idx) = qo;
    *(ushort4*)(xkb + idx) = ko;
    *(ushort4*)(xvb + idx) = vo;
  }
}

// ---------------- weight transpose + bf16 cast: W (K x N) -> WT (N x K) ----------------
__global__ __launch_bounds__(256) void transp_w(const float* __restrict__ W, u16* __restrict__ WT,
                                                int K, int N) {
  __shared__ float tile[32][33];
  const int n0 = blockIdx.x << 5, k0 = blockIdx.y << 5;
  const int c = threadIdx.x & 31, r0 = threadIdx.x >> 5;
#pragma unroll
  for (int j = 0; j < 32; j += 8)
    tile[r0 + j][c] = W[(size_t)(k0 + r0 + j) * N + n0 + c];
  __syncthreads();
#pragma unroll
  for (int j = 0; j < 32; j += 8)
    WT[(size_t)(n0 + r0 + j) * K + k0 + c] = f2bf(tile[c][r0 + j]);
}

// ---------------- GEMM: C(MxN) = A(MxK,bf16) * BT(NxK,bf16)^T, fp32 out ----------------
__global__ __launch_bounds__(256) void gemm_bt(const u16* __restrict__ A, const u16* __restrict__ BT,
                                               float* __restrict__ C, int K, int N) {
  __shared__ u16 As[128 * 32];
  __shared__ u16 Bs[128 * 32];
  const int tid = threadIdx.x;
  const int lane = tid & 63;
  const int w = tid >> 6;
  const int wr = w >> 1, wc = w & 1;
  const int ql = lane & 15, g = lane >> 4;
  const size_t rowM = (size_t)blockIdx.y * 128;
  const size_t colN = (size_t)blockIdx.x * 128;
  const int srow = lane >> 2;
  const int skoff = (lane & 3) << 3;
  f32x4 acc[4][4] = {};
  const u16* ga0 = A + (rowM + w * 32 + srow) * (size_t)K + skoff;
  const u16* gb0 = BT + (colN + w * 32 + srow) * (size_t)K + skoff;
  const int nk = K >> 5;
  for (int kt = 0; kt < nk; ++kt) {
    const int k0 = kt << 5;
#pragma unroll
    for (int j = 0; j < 2; ++j) {
      LOAD_LDS_16B(ga0 + (size_t)j * 16 * K + k0, &As[(w * 2 + j) * 512]);
      LOAD_LDS_16B(gb0 + (size_t)j * 16 * K + k0, &Bs[(w * 2 + j) * 512]);
    }
    __syncthreads();
    bf16x8 af[4], bfr[4];
#pragma unroll
    for (int m2 = 0; m2 < 4; ++m2)
      af[m2] = *(const bf16x8*)&As[(wr * 64 + m2 * 16 + ql) * 32 + g * 8];
#pragma unroll
    for (int n2 = 0; n2 < 4; ++n2)
      bfr[n2] = *(const bf16x8*)&Bs[(wc * 64 + n2 * 16 + ql) * 32 + g * 8];
#pragma unroll
    for (int m2 = 0; m2 < 4; ++m2)
#pragma unroll
      for (int n2 = 0; n2 < 4; ++n2)
        acc[m2][n2] = mfma32(af[m2], bfr[n2], acc[m2][n2]);
    __syncthreads();
  }
#pragma unroll
  for (int m2 = 0; m2 < 4; ++m2) {
#pragma unroll
    for (int n2 = 0; n2 < 4; ++n2) {
      float* cp = C + (rowM + wr * 64 + m2 * 16 + g * 4) * (size_t)N + colN + wc * 64 + n2 * 16 + ql;
#pragma unroll
      for (int i = 0; i < 4; ++i) cp[(size_t)i * N] = acc[m2][n2][i];
    }
  }
}

// ---------------- q/k: rms_norm + rope (+scale), fp32 -> bf16 (b,h,t,d) ----------------
__global__ __launch_bounds__(256) void qk_post(const float* __restrict__ src, u16* __restrict__ dst,
                                               int nh, int srcN, float scale) {
  const int vi = blockIdx.x * 4 + (threadIdx.x >> 6);
  const int l = threadIdx.x & 63;
  const int t = vi & (T_ - 1);
  const int h = (vi >> 11) & (nh - 1);
  const int b = vi / (nh << 11);
  const float* sp = src + (size_t)(b * T_ + t) * srcN + h * HD_;
  float x0 = sp[l], x1 = sp[l + 64];
  float ss = wave_sum(x0 * x0 + x1 * x1);
  float r = rsqrtf(ss * (1.0f / 128.0f) + 1e-8f);
  x0 *= r; x1 *= r;
  float fr = exp2f((float)l * (-13.287712379549449f / 64.0f));
  float ang = (float)t * fr;
  float sn, cs;
  sincosf(ang, &sn, &cs);
  float o0 = (x0 * cs - x1 * sn) * scale;
  float o1 = (x1 * cs + x0 * sn) * scale;
  u16* dp = dst + (size_t)vi * HD_;
  dp[l] = f2bf(o0);
  dp[l + 64] = f2bf(o1);
}

// ---------------- v: rms_norm, store transposed (b,kvh,d,t) bf16 ----------------
__global__ __launch_bounds__(256) void v_post(const float* __restrict__ vf, u16* __restrict__ vtb) {
  __shared__ u16 tile[64 * 130];
  const int blk = blockIdx.x;
  const int bk = blk >> 5;
  const int t0 = (blk & 31) << 6;
  const int b = bk >> 2, kvh = bk & 3;
  const int w = threadIdx.x >> 6, l = threadIdx.x & 63;
  for (int j = 0; j < 16; ++j) {
    const int tl = w * 16 + j;
    const float* sp = vf + (size_t)(b * T_ + t0 + tl) * 512 + kvh * HD_;
    float x0 = sp[l], x1 = sp[l + 64];
    float ss = wave_sum(x0 * x0 + x1 * x1);
    float r = rsqrtf(ss * (1.0f / 128.0f) + 1e-8f);
    tile[tl * 130 + l] = f2bf(x0 * r);
    tile[tl * 130 + 64 + l] = f2bf(x1 * r);
  }
  __syncthreads();
  u16* op = vtb + (size_t)bk * HD_ * T_ + t0;
  for (int idx = threadIdx.x; idx < 64 * 128; idx += 256) {
    const int tl = idx & 63, d = idx >> 6;
    op[(size_t)d * T_ + tl] = tile[tl * 130 + d];
  }
}

// ---------------- flash attention, causal GQA; skips softmax denominator (l2-norm later) ----------------
__global__ __launch_bounds__(64) void attn_fwd(const u16* __restrict__ qh, const u16* __restrict__ kh,
                                               const u16* __restrict__ vt, float* __restrict__ y) {
  const int lane = threadIdx.x;
  const int ql = lane & 15, g = lane >> 4;
  const int bh = blockIdx.y;
  const int b = bh >> 4, h = bh & 15;
  const int kvh = h >> 2;
  const int q0 = blockIdx.x << 4;
  const u16* qp = qh + ((size_t)bh * T_ + q0 + ql) * HD_;
  bf16x8 qf[4];
#pragma unroll
  for (int kk = 0; kk < 4; ++kk) qf[kk] = *(const bf16x8*)(qp + kk * 32 + g * 8);
  const u16* kbase = kh + ((size_t)(b * KVH_ + kvh) * T_) * HD_;
  const u16* vbase = vt + ((size_t)(b * KVH_ + kvh) * HD_) * T_;
  f32x4 acc[8] = {};
  float mrun = -1e30f;
  const int qrow = q0 + ql;
  const int ntiles = (q0 + 47) >> 5;
  for (int kt = 0; kt < ntiles; ++kt) {
    const int kv0 = kt << 5;
    f32x4 st[2] = {};
#pragma unroll
    for (int n0 = 0; n0 < 2; ++n0) {
      const u16* kp = kbase + (size_t)(kv0 + n0 * 16 + ql) * HD_;
#pragma unroll
      for (int kk = 0; kk < 4; ++kk) {
        bf16x8 kfr = *(const bf16x8*)(kp + kk * 32 + g * 8);
        st[n0] = mfma32(kfr, qf[kk], st[n0]);  // S^T tile: lane holds q=ql, kv=n0*16+4g+i
      }
    }
    float sv[8];
    float pmax = -1e30f;
#pragma unroll
    for (int n0 = 0; n0 < 2; ++n0)
#pragma unroll
      for (int i = 0; i < 4; ++i) {
        const int kv = kv0 + n0 * 16 + g * 4 + i;
        float s = (kv <= qrow) ? st[n0][i] : -1e30f;
        sv[n0 * 4 + i] = s;
        pmax = fmaxf(pmax, s);
      }
    pmax = fmaxf(pmax, __shfl_xor(pmax, 16));
    pmax = fmaxf(pmax, __shfl_xor(pmax, 32));
    const float mnew = fmaxf(mrun, pmax);
    const float sc = __expf(mrun - mnew);
    mrun = mnew;
    bf16x4 pf[2];
#pragma unroll
    for (int n0 = 0; n0 < 2; ++n0)
#pragma unroll
      for (int i = 0; i < 4; ++i)
        pf[n0][i] = (short)f2bf(__expf(sv[n0 * 4 + i] - mnew));
    const float s0 = __shfl(sc, g * 4 + 0);
    const float s1 = __shfl(sc, g * 4 + 1);
    const float s2 = __shfl(sc, g * 4 + 2);
    const float s3 = __shfl(sc, g * 4 + 3);
#pragma unroll
    for (int dc = 0; dc < 8; ++dc) {
      acc[dc][0] *= s0; acc[dc][1] *= s1; acc[dc][2] *= s2; acc[dc][3] *= s3;
    }
#pragma unroll
    for (int n0 = 0; n0 < 2; ++n0) {
      const u16* vp = vbase + kv0 + n0 * 16 + g * 4;
#pragma unroll
      for (int dc = 0; dc < 8; ++dc) {
        bf16x4 vfr = *(const bf16x4*)(vp + (size_t)(dc * 16 + ql) * T_);
        acc[dc] = mfma16(pf[n0], vfr, acc[dc]);  // Y: lane holds q=q0+4g+i, d=dc*16+ql
      }
    }
  }
  float* yp = y + ((size_t)bh * T_ + q0 + g * 4) * HD_;
#pragma unroll
  for (int dc = 0; dc < 8; ++dc)
#pragma unroll
    for (int i = 0; i < 4; ++i)
      yp[(size_t)i * HD_ + dc * 16 + ql] = acc[dc][i];
}

// ---------------- l2-norm * gate -> bf16 rows for Wo GEMM ----------------
__global__ __launch_bounds__(256) void post_attn(const float* __restrict__ y, const float* __restrict__ qg,
                                                 u16* __restrict__ A2) {
  const int vi = blockIdx.x * 4 + (threadIdx.x >> 6);  // (b*H+h)*T + t
  const int l = threadIdx.x & 63;
  const int t = vi & (T_ - 1);
  const int h = (vi >> 11) & (H_ - 1);
  const int b = vi >> 15;
  const float* yp = y + (size_t)vi * HD_;
  float y0 = yp[l], y1 = yp[l + 64];
  float ss = wave_sum(y0 * y0 + y1 * y1);
  float sc = 1.0f / fmaxf(sqrtf(ss), 1e-12f);
  const size_t row = (size_t)b * T_ + t;
  const float* gp = qg + row * 4096 + 2048 + h * HD_;
  u16* ap = A2 + row * 2048 + h * HD_;
  ap[l] = f2bf(y0 * sc * gp[l]);
  ap[l + 64] = f2bf(y1 * sc * gp[l + 64]);
}

// ---------------- final rms_norm / sqrt(48) ----------------
__global__ __launch_bounds__(256) void final_norm(const float* __restrict__ xp, float* __restrict__ out) {
  __shared__ float red[4];
  const size_t row = blockIdx.x;
  const float* p = xp + row * 2048;
  const int tid = threadIdx.x;
  float4 a = *(const float4*)(p + tid * 4);
  float4 b = *(const float4*)(p + 1024 + tid * 4);
  float ss = a.x * a.x + a.y * a.y + a.z * a.z + a.w * a.w +
             b.x * b.x + b.y * b.y + b.z * b.z + b.w * b.w;
  ss = wave_sum(ss);
  if ((tid & 63) == 0) red[tid >> 6] = ss;
  __syncthreads();
  float tot = red[0] + red[1] + red[2] + red[3];
  float r = rsqrtf(tot * (1.0f / 2048.0f) + 1e-8f) * 0.14433756729740643f;
  float* op = out + row * 2048;
  float4 oa = {a.x * r, a.y * r, a.z * r, a.w * r};
  float4 ob = {b.x * r, b.y * r, b.z * r, b.w * r};
  *(float4*)(op + tid * 4) = oa;
  *(float4*)(op + 1024 + tid * 4) = ob;
}

extern "C" void kernel_launch(void* const* d_in, const int* in_sizes, int n_in,
                              void* d_out, int out_size, void* d_ws, size_t ws_size,
                              hipStream_t stream) {
  (void)in_sizes; (void)n_in; (void)out_size; (void)ws_size;
  const float* xq = (const float*)d_in[0];
  const float* xk = (const float*)d_in[1];
  const float* xv = (const float*)d_in[2];
  const float* Wq = (const float*)d_in[3];
  const float* Wk = (const float*)d_in[4];
  const float* Wv = (const float*)d_in[5];
  const float* Wg = (const float*)d_in[6];
  const float* Wo = (const float*)d_in[7];
  const float* mk = (const float*)d_in[8];
  const float* mv = (const float*)d_in[9];
  float* out = (float*)d_out;
  char* ws = (char*)d_ws;

  // workspace layout (total 188,743,680 B); later-stage buffers alias dead early ones
  u16*   xqb  = (u16*)(ws + 0);
  u16*   xkb  = (u16*)(ws + 16777216);
  u16*   xvb  = (u16*)(ws + 33554432);
  u16*   WqgT = (u16*)(ws + 50331648);
  u16*   WkT  = (u16*)(ws + 67108864);
  u16*   WvT  = (u16*)(ws + 69206016);
  u16*   WoT  = (u16*)(ws + 71303168);
  float* qg   = (float*)(ws + 79691776);
  float* kf   = (float*)(ws + 146800640);
  float* vf   = (float*)(ws + 155189248);
  u16*   qhat = (u16*)(ws + 163577856);
  u16*   khat = (u16*)(ws + 180355072);
  u16*   vhat = (u16*)(ws + 184549376);
  float* yb   = (float*)(ws + 0);         // alias xqb+xkb (dead after proj GEMMs)
  u16*   A2   = (u16*)(ws + 33554432);    // alias xvb
  float* op   = (float*)(ws + 79691776);  // alias qg (dead after post_attn)

  prep_x<<<2048, 256, 0, stream>>>(xq, xk, xv, mk, mv, xqb, xkb, xvb);
  transp_w<<<dim3(64, 64), 256, 0, stream>>>(Wq, WqgT, 2048, 2048);
  transp_w<<<dim3(64, 64), 256, 0, stream>>>(Wg, WqgT + (size_t)2048 * 2048, 2048, 2048);
  transp_w<<<dim3(16, 64), 256, 0, stream>>>(Wk, WkT, 2048, 512);
  transp_w<<<dim3(16, 64), 256, 0, stream>>>(Wv, WvT, 2048, 512);
  transp_w<<<dim3(64, 64), 256, 0, stream>>>(Wo, WoT, 2048, 2048);
  gemm_bt<<<dim3(32, 32), 256, 0, stream>>>(xqb, WqgT, qg, 2048, 4096);
  gemm_bt<<<dim3(4, 32), 256, 0, stream>>>(xkb, WkT, kf, 2048, 512);
  gemm_bt<<<dim3(4, 32), 256, 0, stream>>>(xvb, WvT, vf, 2048, 512);
  qk_post<<<16384, 256, 0, stream>>>(qg, qhat, H_, 4096, 0.08838834764831845f);
  qk_post<<<4096, 256, 0, stream>>>(kf, khat, KVH_, 512, 1.0f);
  v_post<<<256, 256, 0, stream>>>(vf, vhat);
  attn_fwd<<<dim3(128, 32), 64, 0, stream>>>(qhat, khat, vhat, yb);
  post_attn<<<16384, 256, 0, stream>>>(yb, qg, A2);
  gemm_bt<<<dim3(16, 32), 256, 0, stream>>>(A2, WoT, op, 2048, 2048);
  final_norm<<<4096, 256, 0, stream>>>(op, out);
}

// Round 4
// 607.878 us; speedup vs baseline: 1.9488x; 1.9488x over previous
//
#include <hip/hip_runtime.h>

#define DEV static __device__ __forceinline__

typedef unsigned short u16;
typedef short bf16x4 __attribute__((ext_vector_type(4)));
typedef short bf16x8 __attribute__((ext_vector_type(8)));
typedef float f32x4 __attribute__((ext_vector_type(4)));
typedef float f32x16 __attribute__((ext_vector_type(16)));

#define B_   2
#define T_   2048
#define D_   2048
#define H_   16
#define KVH_ 4
#define HD_  128

DEV u16 f2bf(float f) {
  union { float f; unsigned u; } v; v.f = f;
  unsigned r = v.u + 0x7fffu + ((v.u >> 16) & 1u);
  return (u16)(r >> 16);
}

DEV float wave_sum(float v) {
#pragma unroll
  for (int o = 1; o < 64; o <<= 1) v += __shfl_xor(v, o);
  return v;
}

#define LOAD_LDS_16B(gptr, lptr)                                                                  \
  __builtin_amdgcn_global_load_lds((const __attribute__((address_space(1))) unsigned int*)(gptr), \
                                   (__attribute__((address_space(3))) unsigned int*)(lptr), 16, 0, 0)

DEV f32x4 mfma32(bf16x8 a, bf16x8 b, f32x4 c) {
  return __builtin_amdgcn_mfma_f32_16x16x32_bf16(a, b, c, 0, 0, 0);
}
DEV f32x16 mfma3216(bf16x8 a, bf16x8 b, f32x16 c) {
  return __builtin_amdgcn_mfma_f32_32x32x16_bf16(a, b, c, 0, 0, 0);
}

DEV unsigned cvtpk(float lo, float hi) {
  unsigned r;
  asm("v_cvt_pk_bf16_f32 %0, %1, %2" : "=v"(r) : "v"(lo), "v"(hi));
  return r;
}

#if __has_builtin(__builtin_amdgcn_permlane32_swap)
DEV void swap32(unsigned& a, unsigned& b, int) {
  typedef int v2i __attribute__((ext_vector_type(2)));
  v2i r = __builtin_amdgcn_permlane32_swap((int)a, (int)b, false, false);
  a = (unsigned)r.x;
  b = (unsigned)r.y;
}
#else
DEV void swap32(unsigned& a, unsigned& b, int hi) {
  const unsigned as = (unsigned)__shfl_xor((int)a, 32);
  const unsigned bs = (unsigned)__shfl_xor((int)b, 32);
  const unsigned na = hi ? bs : a;
  const unsigned nb = hi ? b : as;
  a = na;
  b = nb;
}
#endif

// ---------------- prep: token-shift mix + bf16 cast ----------------
__global__ __launch_bounds__(256) void prep_x(const float* __restrict__ xq, const float* __restrict__ xk,
                                              const float* __restrict__ xv, const float* __restrict__ mk,
                                              const float* __restrict__ mv, u16* __restrict__ xqb,
                                              u16* __restrict__ xkb, u16* __restrict__ xvb) {
  const int n4 = (B_ * T_ * D_) >> 2;
  for (int i = blockIdx.x * blockDim.x + threadIdx.x; i < n4; i += gridDim.x * blockDim.x) {
    const int idx = i << 2;
    const int d = idx & (D_ - 1);
    const int t = (idx >> 11) & (T_ - 1);
    float4 q = *(const float4*)(xq + idx);
    float4 k = *(const float4*)(xk + idx);
    float4 v = *(const float4*)(xv + idx);
    float4 kp = {0, 0, 0, 0}, vp = {0, 0, 0, 0};
    if (t > 0) {
      kp = *(const float4*)(xk + idx - D_);
      vp = *(const float4*)(xv + idx - D_);
    }
    float4 cmk = *(const float4*)(mk + d);
    float4 cmv = *(const float4*)(mv + d);
    ushort4 qo, ko, vo;
    qo.x = f2bf(q.x); qo.y = f2bf(q.y); qo.z = f2bf(q.z); qo.w = f2bf(q.w);
    ko.x = f2bf(k.x + cmk.x * (kp.x - k.x));
    ko.y = f2bf(k.y + cmk.y * (kp.y - k.y));
    ko.z = f2bf(k.z + cmk.z * (kp.z - k.z));
    ko.w = f2bf(k.w + cmk.w * (kp.w - k.w));
    vo.x = f2bf(v.x + cmv.x * (vp.x - v.x));
    vo.y = f2bf(v.y + cmv.y * (vp.y - v.y));
    vo.z = f2bf(v.z + cmv.z * (vp.z - v.z));
    vo.w = f2bf(v.w + cmv.w * (vp.w - v.w));
    *(ushort4*)(xqb + idx) = qo;
    *(ushort4*)(xkb + idx) = ko;
    *(ushort4*)(xvb + idx) = vo;
  }
}

// ---------------- weight transpose + bf16 cast: W (K x N) -> WT (N x K) ----------------
__global__ __launch_bounds__(256) void transp_w(const float* __restrict__ W, u16* __restrict__ WT,
                                                int K, int N) {
  __shared__ float tile[32][33];
  const int n0 = blockIdx.x << 5, k0 = blockIdx.y << 5;
  const int c = threadIdx.x & 31, r0 = threadIdx.x >> 5;
#pragma unroll
  for (int j = 0; j < 32; j += 8)
    tile[r0 + j][c] = W[(size_t)(k0 + r0 + j) * N + n0 + c];
  __syncthreads();
#pragma unroll
  for (int j = 0; j < 32; j += 8)
    WT[(size_t)(n0 + r0 + j) * K + k0 + c] = f2bf(tile[c][r0 + j]);
}

// ---------------- GEMM: C(MxN) = A(MxK,bf16) * BT(NxK,bf16)^T, fp32 out ----------------
__global__ __launch_bounds__(256) void gemm_bt(const u16* __restrict__ A, const u16* __restrict__ BT,
                                               float* __restrict__ C, int K, int N) {
  __shared__ u16 As[128 * 32];
  __shared__ u16 Bs[128 * 32];
  const int tid = threadIdx.x;
  const int lane = tid & 63;
  const int w = tid >> 6;
  const int wr = w >> 1, wc = w & 1;
  const int ql = lane & 15, g = lane >> 4;
  const size_t rowM = (size_t)blockIdx.y * 128;
  const size_t colN = (size_t)blockIdx.x * 128;
  const int srow = lane >> 2;
  const int skoff = (lane & 3) << 3;
  f32x4 acc[4][4] = {};
  const u16* ga0 = A + (rowM + w * 32 + srow) * (size_t)K + skoff;
  const u16* gb0 = BT + (colN + w * 32 + srow) * (size_t)K + skoff;
  const int nk = K >> 5;
  for (int kt = 0; kt < nk; ++kt) {
    const int k0 = kt << 5;
#pragma unroll
    for (int j = 0; j < 2; ++j) {
      LOAD_LDS_16B(ga0 + (size_t)j * 16 * K + k0, &As[(w * 2 + j) * 512]);
      LOAD_LDS_16B(gb0 + (size_t)j * 16 * K + k0, &Bs[(w * 2 + j) * 512]);
    }
    __syncthreads();
    bf16x8 af[4], bfr[4];
#pragma unroll
    for (int m2 = 0; m2 < 4; ++m2)
      af[m2] = *(const bf16x8*)&As[(wr * 64 + m2 * 16 + ql) * 32 + g * 8];
#pragma unroll
    for (int n2 = 0; n2 < 4; ++n2)
      bfr[n2] = *(const bf16x8*)&Bs[(wc * 64 + n2 * 16 + ql) * 32 + g * 8];
#pragma unroll
    for (int m2 = 0; m2 < 4; ++m2)
#pragma unroll
      for (int n2 = 0; n2 < 4; ++n2)
        acc[m2][n2] = mfma32(af[m2], bfr[n2], acc[m2][n2]);
    __syncthreads();
  }
#pragma unroll
  for (int m2 = 0; m2 < 4; ++m2) {
#pragma unroll
    for (int n2 = 0; n2 < 4; ++n2) {
      float* cp = C + (rowM + wr * 64 + m2 * 16 + g * 4) * (size_t)N + colN + wc * 64 + n2 * 16 + ql;
#pragma unroll
      for (int i = 0; i < 4; ++i) cp[(size_t)i * N] = acc[m2][n2][i];
    }
  }
}

// ---------------- q/k: rms_norm + rope (+scale), fp32 -> bf16 (b,h,t,d) ----------------
__global__ __launch_bounds__(256) void qk_post(const float* __restrict__ src, u16* __restrict__ dst,
                                               int nh, int srcN, float scale) {
  const int vi = blockIdx.x * 4 + (threadIdx.x >> 6);
  const int l = threadIdx.x & 63;
  const int t = vi & (T_ - 1);
  const int h = (vi >> 11) & (nh - 1);
  const int b = vi / (nh << 11);
  const float* sp = src + (size_t)(b * T_ + t) * srcN + h * HD_;
  float x0 = sp[l], x1 = sp[l + 64];
  float ss = wave_sum(x0 * x0 + x1 * x1);
  float r = rsqrtf(ss * (1.0f / 128.0f) + 1e-8f);
  x0 *= r; x1 *= r;
  float fr = exp2f((float)l * (-13.287712379549449f / 64.0f));
  float ang = (float)t * fr;
  float sn, cs;
  sincosf(ang, &sn, &cs);
  float o0 = (x0 * cs - x1 * sn) * scale;
  float o1 = (x1 * cs + x0 * sn) * scale;
  u16* dp = dst + (size_t)vi * HD_;
  dp[l] = f2bf(o0);
  dp[l + 64] = f2bf(o1);
}

// ---------------- v: rms_norm, store transposed (b,kvh,d,t) bf16 ----------------
__global__ __launch_bounds__(256) void v_post(const float* __restrict__ vf, u16* __restrict__ vtb) {
  __shared__ u16 tile[64 * 130];
  const int blk = blockIdx.x;
  const int bk = blk >> 5;
  const int t0 = (blk & 31) << 6;
  const int b = bk >> 2, kvh = bk & 3;
  const int w = threadIdx.x >> 6, l = threadIdx.x & 63;
  for (int j = 0; j < 16; ++j) {
    const int tl = w * 16 + j;
    const float* sp = vf + (size_t)(b * T_ + t0 + tl) * 512 + kvh * HD_;
    float x0 = sp[l], x1 = sp[l + 64];
    float ss = wave_sum(x0 * x0 + x1 * x1);
    float r = rsqrtf(ss * (1.0f / 128.0f) + 1e-8f);
    tile[tl * 130 + l] = f2bf(x0 * r);
    tile[tl * 130 + 64 + l] = f2bf(x1 * r);
  }
  __syncthreads();
  u16* op = vtb + (size_t)bk * HD_ * T_ + t0;
  for (int idx = threadIdx.x; idx < 64 * 128; idx += 256) {
    const int tl = idx & 63, d = idx >> 6;
    op[(size_t)d * T_ + tl] = tile[tl * 130 + d];
  }
}

// ---------------- flash attention v2: 4 waves x 32 q-rows, 32x32 MFMA, no-max exp2,
// K/V LDS-staged (XOR-swizzled) via global_load_lds, double-buffered ----------------
__global__ __launch_bounds__(256) void attn_fwd2(const u16* __restrict__ qh, const u16* __restrict__ kh,
                                                 const u16* __restrict__ vt, float* __restrict__ y) {
  __shared__ alignas(16) u16 Ks[2][64 * 128];  // [kv][d], byte ^= ((kv&15)<<4)
  __shared__ alignas(16) u16 Vs[2][128 * 64];  // [d][kv], byte ^= ((d&7)<<4)
  const int tid = threadIdx.x;
  const int lane = tid & 63;
  const int w = tid >> 6;
  const int l31 = lane & 31;
  const int hi = lane >> 5;
  const int bh = blockIdx.y;
  const int b = bh >> 4, h = bh & 15;
  const int kvh = h >> 2;
  const int q0 = (int)(gridDim.x - 1 - blockIdx.x) * 128;  // heavy blocks first
  const int qw = q0 + w * 32;
  const u16* kbase = kh + (size_t)(b * KVH_ + kvh) * T_ * HD_;
  const u16* vbase = vt + (size_t)(b * KVH_ + kvh) * HD_ * T_;

  // Q fragments: lane holds Q[qw+l31][ks2*16 + hi*8 + j]
  const u16* qp = qh + ((size_t)bh * T_ + qw + l31) * HD_ + hi * 8;
  bf16x8 qf[8];
#pragma unroll
  for (int ks2 = 0; ks2 < 8; ++ks2) qf[ks2] = *(const bf16x8*)(qp + ks2 * 16);

  f32x16 acc[4] = {};
  const int ntiles = (q0 >> 6) + 2;

#define STAGE_TILE(buf, kv0s)                                                                       \
  {                                                                                                 \
    _Pragma("unroll") for (int i = 0; i < 4; ++i) {                                                 \
      const int row = i * 16 + w * 4 + (lane >> 4);                                                 \
      const int sl = ((lane & 15) ^ (row & 15)) * 8;                                                \
      LOAD_LDS_16B(kbase + (size_t)((kv0s) + row) * HD_ + sl, &Ks[buf][i * 2048 + w * 512]);        \
    }                                                                                               \
    _Pragma("unroll") for (int i = 0; i < 4; ++i) {                                                 \
      const int dd = i * 32 + w * 8 + (lane >> 3);                                                  \
      const int sl = ((lane & 7) ^ (dd & 7)) * 8;                                                   \
      LOAD_LDS_16B(vbase + (size_t)dd * T_ + (kv0s) + sl, &Vs[buf][i * 2048 + w * 512]);            \
    }                                                                                               \
  }

  STAGE_TILE(0, 0);
  __syncthreads();

  for (int kt = 0; kt < ntiles; ++kt) {
    const int cur = kt & 1;
    if (kt + 1 < ntiles) STAGE_TILE(cur ^ 1, (kt + 1) * 64);
    const int kv0 = kt * 64;
    if (kv0 <= qw + 31) {
#pragma unroll
      for (int s = 0; s < 2; ++s) {
        const int kvs = kv0 + s * 32;
        if (kvs <= qw + 31) {
          // QK^T (swapped): S^T[kv][q]; lane: q=l31, kv=(r&3)+8*(r>>2)+4*hi
          f32x16 st = {};
          const u16* krow = &Ks[cur][(s * 32 + l31) * 128];
          const int rsw = (s * 32 + l31) & 15;
          __builtin_amdgcn_s_setprio(1);
#pragma unroll
          for (int ks2 = 0; ks2 < 8; ++ks2) {
            bf16x8 kf = *(const bf16x8*)(krow + (((ks2 * 2 + hi) ^ rsw) * 8));
            st = mfma3216(kf, qf[ks2], st);
          }
          __builtin_amdgcn_s_setprio(0);
          // mask + exp2 (no max subtraction: |s|<=16.3, l2-norm cancels scale)
          float p[16];
#pragma unroll
          for (int r = 0; r < 16; ++r) {
            const int kv = kvs + (r & 3) + 8 * (r >> 2) + 4 * hi;
            const float e = __builtin_amdgcn_exp2f(st[r]);
            p[r] = (kv <= qw + l31) ? e : 0.0f;
          }
          // pack P -> A-fragments (cvt_pk pairs + permlane32 half-swap)
          bf16x8 pa[2];
#pragma unroll
          for (int ks = 0; ks < 2; ++ks) {
            unsigned X = cvtpk(p[8 * ks + 0], p[8 * ks + 1]);
            unsigned Z = cvtpk(p[8 * ks + 2], p[8 * ks + 3]);
            unsigned Y = cvtpk(p[8 * ks + 4], p[8 * ks + 5]);
            unsigned W = cvtpk(p[8 * ks + 6], p[8 * ks + 7]);
            swap32(X, Y, hi);
            swap32(Z, W, hi);
            union { unsigned u[4]; bf16x8 h; } pu;
            pu.u[0] = X; pu.u[1] = Z; pu.u[2] = Y; pu.u[3] = W;
            pa[ks] = pu.h;
          }
          // PV: Y[q][d] += P * V
          __builtin_amdgcn_s_setprio(1);
#pragma unroll
          for (int dt = 0; dt < 4; ++dt) {
            const u16* vrow = &Vs[cur][(dt * 32 + l31) * 64];
            const int vsw = (dt * 32 + l31) & 7;
#pragma unroll
            for (int ks = 0; ks < 2; ++ks) {
              bf16x8 vf = *(const bf16x8*)(vrow + (((s * 4 + ks * 2 + hi) ^ vsw) * 8));
              acc[dt] = mfma3216(pa[ks], vf, acc[dt]);
            }
          }
          __builtin_amdgcn_s_setprio(0);
        }
      }
    }
    __syncthreads();
  }
#undef STAGE_TILE

  // epilogue: lane holds q=(r&3)+8*(r>>2)+4*hi, d=dt*32+l31
  float* yp = y + ((size_t)bh * T_ + qw) * HD_;
#pragma unroll
  for (int dt = 0; dt < 4; ++dt)
#pragma unroll
    for (int r = 0; r < 16; ++r) {
      const int q = (r & 3) + 8 * (r >> 2) + 4 * hi;
      yp[(size_t)q * HD_ + dt * 32 + l31] = acc[dt][r];
    }
}

// ---------------- l2-norm * gate -> bf16 rows for Wo GEMM ----------------
__global__ __launch_bounds__(256) void post_attn(const float* __restrict__ y, const float* __restrict__ qg,
                                                 u16* __restrict__ A2) {
  const int vi = blockIdx.x * 4 + (threadIdx.x >> 6);  // (b*H+h)*T + t
  const int l = threadIdx.x & 63;
  const int t = vi & (T_ - 1);
  const int h = (vi >> 11) & (H_ - 1);
  const int b = vi >> 15;
  const float* yp = y + (size_t)vi * HD_;
  float y0 = yp[l], y1 = yp[l + 64];
  float ss = wave_sum(y0 * y0 + y1 * y1);
  float sc = 1.0f / fmaxf(sqrtf(ss), 1e-12f);
  const size_t row = (size_t)b * T_ + t;
  const float* gp = qg + row * 4096 + 2048 + h * HD_;
  u16* ap = A2 + row * 2048 + h * HD_;
  ap[l] = f2bf(y0 * sc * gp[l]);
  ap[l + 64] = f2bf(y1 * sc * gp[l + 64]);
}

// ---------------- final rms_norm / sqrt(48) ----------------
__global__ __launch_bounds__(256) void final_norm(const float* __restrict__ xp, float* __restrict__ out) {
  __shared__ float red[4];
  const size_t row = blockIdx.x;
  const float* p = xp + row * 2048;
  const int tid = threadIdx.x;
  float4 a = *(const float4*)(p + tid * 4);
  float4 b = *(const float4*)(p + 1024 + tid * 4);
  float ss = a.x * a.x + a.y * a.y + a.z * a.z + a.w * a.w +
             b.x * b.x + b.y * b.y + b.z * b.z + b.w * b.w;
  ss = wave_sum(ss);
  if ((tid & 63) == 0) red[tid >> 6] = ss;
  __syncthreads();
  float tot = red[0] + red[1] + red[2] + red[3];
  float r = rsqrtf(tot * (1.0f / 2048.0f) + 1e-8f) * 0.14433756729740643f;
  float* op = out + row * 2048;
  float4 oa = {a.x * r, a.y * r, a.z * r, a.w * r};
  float4 ob = {b.x * r, b.y * r, b.z * r, b.w * r};
  *(float4*)(op + tid * 4) = oa;
  *(float4*)(op + 1024 + tid * 4) = ob;
}

extern "C" void kernel_launch(void* const* d_in, const int* in_sizes, int n_in,
                              void* d_out, int out_size, void* d_ws, size_t ws_size,
                              hipStream_t stream) {
  (void)in_sizes; (void)n_in; (void)out_size; (void)ws_size;
  const float* xq = (const float*)d_in[0];
  const float* xk = (const float*)d_in[1];
  const float* xv = (const float*)d_in[2];
  const float* Wq = (const float*)d_in[3];
  const float* Wk = (const float*)d_in[4];
  const float* Wv = (const float*)d_in[5];
  const float* Wg = (const float*)d_in[6];
  const float* Wo = (const float*)d_in[7];
  const float* mk = (const float*)d_in[8];
  const float* mv = (const float*)d_in[9];
  float* out = (float*)d_out;
  char* ws = (char*)d_ws;

  // workspace layout (total 188,743,680 B); later-stage buffers alias dead early ones
  u16*   xqb  = (u16*)(ws + 0);
  u16*   xkb  = (u16*)(ws + 16777216);
  u16*   xvb  = (u16*)(ws + 33554432);
  u16*   WqgT = (u16*)(ws + 50331648);
  u16*   WkT  = (u16*)(ws + 67108864);
  u16*   WvT  = (u16*)(ws + 69206016);
  u16*   WoT  = (u16*)(ws + 71303168);
  float* qg   = (float*)(ws + 79691776);
  float* kf   = (float*)(ws + 146800640);
  float* vf   = (float*)(ws + 155189248);
  u16*   qhat = (u16*)(ws + 163577856);
  u16*   khat = (u16*)(ws + 180355072);
  u16*   vhat = (u16*)(ws + 184549376);
  float* yb   = (float*)(ws + 0);         // alias xqb+xkb (dead after proj GEMMs)
  u16*   A2   = (u16*)(ws + 33554432);    // alias xvb
  float* op   = (float*)(ws + 79691776);  // alias qg (dead after post_attn)

  prep_x<<<2048, 256, 0, stream>>>(xq, xk, xv, mk, mv, xqb, xkb, xvb);
  transp_w<<<dim3(64, 64), 256, 0, stream>>>(Wq, WqgT, 2048, 2048);
  transp_w<<<dim3(64, 64), 256, 0, stream>>>(Wg, WqgT + (size_t)2048 * 2048, 2048, 2048);
  transp_w<<<dim3(16, 64), 256, 0, stream>>>(Wk, WkT, 2048, 512);
  transp_w<<<dim3(16, 64), 256, 0, stream>>>(Wv, WvT, 2048, 512);
  transp_w<<<dim3(64, 64), 256, 0, stream>>>(Wo, WoT, 2048, 2048);
  gemm_bt<<<dim3(32, 32), 256, 0, stream>>>(xqb, WqgT, qg, 2048, 4096);
  gemm_bt<<<dim3(4, 32), 256, 0, stream>>>(xkb, WkT, kf, 2048, 512);
  gemm_bt<<<dim3(4, 32), 256, 0, stream>>>(xvb, WvT, vf, 2048, 512);
  // q-scale = (1/sqrt(128)) * log2(e): attention uses raw exp2 (no max-sub; l2-norm cancels scale)
  qk_post<<<16384, 256, 0, stream>>>(qg, qhat, H_, 4096, 0.12751743558136166f);
  qk_post<<<4096, 256, 0, stream>>>(kf, khat, KVH_, 512, 1.0f);
  v_post<<<256, 256, 0, stream>>>(vf, vhat);
  attn_fwd2<<<dim3(16, 32), 256, 0, stream>>>(qhat, khat, vhat, yb);
  post_attn<<<16384, 256, 0, stream>>>(yb, qg, A2);
  gemm_bt<<<dim3(16, 32), 256, 0, stream>>>(A2, WoT, op, 2048, 2048);
  final_norm<<<4096, 256, 0, stream>>>(op, out);
}